// Round 2
// baseline (507.671 us; speedup 1.0000x reference)
//
#include <hip/hip_runtime.h>

// Problem constants (from reference)
#define NNZ        524288
#define DDIM       256
#define N_MENTIONS 65536

// One wave (64 lanes) per mention row. Lane l owns float4 columns [4l, 4l+4).
// spm_rows is sorted -> segment per output row is contiguous; binary search
// finds [start,end). No atomics, deterministic fp32 accumulation.
__global__ __launch_bounds__(256) void mention_segsum_kernel(
    const float* __restrict__ token_ft,   // [N_TOKENS, 256]
    const int*   __restrict__ token_code, // [NNZ]
    const int*   __restrict__ spm_rows,   // [NNZ] sorted
    const float* __restrict__ spm_vals,   // [NNZ]
    float*       __restrict__ out)        // [N_MENTIONS, 256]
{
    const int wave = threadIdx.x >> 6;            // 0..3
    const int lane = threadIdx.x & 63;
    const int row  = (blockIdx.x << 2) + wave;    // mention row, < 65536

    // lower_bound(spm_rows, row) -> start; lower_bound(spm_rows, row+1) -> end.
    // Wave-uniform control flow; all lanes search redundantly (same addresses,
    // HW broadcasts the loads).
    int lo = 0, hi = NNZ;
    while (lo < hi) {
        int mid = (lo + hi) >> 1;
        if (spm_rows[mid] < row) lo = mid + 1; else hi = mid;
    }
    const int start = lo;
    hi = NNZ;
    while (lo < hi) {
        int mid = (lo + hi) >> 1;
        if (spm_rows[mid] < row + 1) lo = mid + 1; else hi = mid;
    }
    const int end = lo;

    float4 acc = make_float4(0.f, 0.f, 0.f, 0.f);

    // Process the segment in chunks of <=64 nnz: lane i pre-loads pair i,
    // then all lanes consume via __shfl broadcast. This keeps the gather
    // addresses register-resident for the whole chunk (no per-iteration
    // dependent index load).
    for (int base = start; base < end; base += 64) {
        const int count = min(64, end - base);
        const int k = base + lane;
        int   code_l = 0;
        float val_l  = 0.f;
        if (lane < count) {
            code_l = token_code[k];
            val_l  = spm_vals[k];
        }
        for (int i = 0; i < count; ++i) {
            const int   code = __shfl(code_l, i);
            const float v    = __shfl(val_l, i);
            const float4 ft = ((const float4*)(token_ft + (size_t)code * DDIM))[lane];
            acc.x += ft.x * v;
            acc.y += ft.y * v;
            acc.z += ft.z * v;
            acc.w += ft.w * v;
        }
    }

    // Always store (zeros for empty segments — d_out is poisoned by harness).
    ((float4*)(out + (size_t)row * DDIM))[lane] = acc;
}

extern "C" void kernel_launch(void* const* d_in, const int* in_sizes, int n_in,
                              void* d_out, int out_size, void* d_ws, size_t ws_size,
                              hipStream_t stream) {
    const float* token_ft   = (const float*)d_in[0];
    const int*   token_code = (const int*)d_in[1];
    const int*   spm_rows   = (const int*)d_in[2];
    const float* spm_vals   = (const float*)d_in[3];
    float*       out        = (float*)d_out;

    // 65536 rows, 4 waves (rows) per 256-thread block -> 16384 blocks
    dim3 grid(N_MENTIONS / 4);
    dim3 block(256);
    mention_segsum_kernel<<<grid, block, 0, stream>>>(
        token_ft, token_code, spm_rows, spm_vals, out);
}

// Round 3
// 396.926 us; speedup vs baseline: 1.2790x; 1.2790x over previous
//
#include <hip/hip_runtime.h>

// Problem constants (from reference)
#define NNZ        524288
#define DDIM       256
#define N_MENTIONS 65536

// ---------------------------------------------------------------------------
// Kernel 1: build row_start[0 .. N_MENTIONS] in d_ws from sorted spm_rows.
// Thread j (0..NNZ) writes row_start[r] = j for all r in (prev, cur], where
// prev = spm_rows[j-1] (-1 for j==0), cur = spm_rows[j] (N_MENTIONS for j==NNZ).
// Union over j covers [0, N_MENTIONS] exactly once (disjoint ranges), so the
// 0xAA-poisoned workspace is fully overwritten every call.
// ---------------------------------------------------------------------------
__global__ __launch_bounds__(256) void build_row_start_kernel(
    const int* __restrict__ spm_rows,   // [NNZ] sorted
    int*       __restrict__ row_start)  // [N_MENTIONS + 1]
{
    const int j = blockIdx.x * blockDim.x + threadIdx.x;
    if (j > NNZ) return;
    const int cur  = (j < NNZ) ? spm_rows[j] : N_MENTIONS;
    const int prev = (j > 0)   ? spm_rows[j - 1] : -1;
    for (int r = prev + 1; r <= cur; ++r) row_start[r] = j;
}

// ---------------------------------------------------------------------------
// Kernel 2: one wave per mention row. Lane l owns float4 columns [4l, 4l+4).
// start/end come from row_start (2 wave-uniform loads). Codes/vals for up to
// 64 nnz are lane-loaded once, then consumed via __shfl broadcast; gather
// loop unrolled x4 so 4 independent 1-KiB row reads are in flight per wait.
// ---------------------------------------------------------------------------
__global__ __launch_bounds__(256) void mention_csr_kernel(
    const float* __restrict__ token_ft,   // [N_TOKENS, 256]
    const int*   __restrict__ token_code, // [NNZ]
    const float* __restrict__ spm_vals,   // [NNZ]
    const int*   __restrict__ row_start,  // [N_MENTIONS + 1]
    float*       __restrict__ out)        // [N_MENTIONS, 256]
{
    const int wave = threadIdx.x >> 6;            // 0..3
    const int lane = threadIdx.x & 63;
    const int row  = (blockIdx.x << 2) + wave;    // mention row

    const int start = row_start[row];
    const int end   = row_start[row + 1];

    float4 acc0 = make_float4(0.f, 0.f, 0.f, 0.f);
    float4 acc1 = make_float4(0.f, 0.f, 0.f, 0.f);

    for (int base = start; base < end; base += 64) {
        const int count = min(64, end - base);
        int   code_l = 0;
        float val_l  = 0.f;
        if (lane < count) {
            code_l = token_code[base + lane];
            val_l  = spm_vals[base + lane];
        }

        int i = 0;
        for (; i + 4 <= count; i += 4) {
            const int   c0 = __shfl(code_l, i);
            const int   c1 = __shfl(code_l, i + 1);
            const int   c2 = __shfl(code_l, i + 2);
            const int   c3 = __shfl(code_l, i + 3);
            const float v0 = __shfl(val_l, i);
            const float v1 = __shfl(val_l, i + 1);
            const float v2 = __shfl(val_l, i + 2);
            const float v3 = __shfl(val_l, i + 3);
            const float4 f0 = ((const float4*)(token_ft + (size_t)c0 * DDIM))[lane];
            const float4 f1 = ((const float4*)(token_ft + (size_t)c1 * DDIM))[lane];
            const float4 f2 = ((const float4*)(token_ft + (size_t)c2 * DDIM))[lane];
            const float4 f3 = ((const float4*)(token_ft + (size_t)c3 * DDIM))[lane];
            acc0.x += f0.x * v0; acc0.y += f0.y * v0; acc0.z += f0.z * v0; acc0.w += f0.w * v0;
            acc1.x += f1.x * v1; acc1.y += f1.y * v1; acc1.z += f1.z * v1; acc1.w += f1.w * v1;
            acc0.x += f2.x * v2; acc0.y += f2.y * v2; acc0.z += f2.z * v2; acc0.w += f2.w * v2;
            acc1.x += f3.x * v3; acc1.y += f3.y * v3; acc1.z += f3.z * v3; acc1.w += f3.w * v3;
        }
        for (; i < count; ++i) {
            const int   c = __shfl(code_l, i);
            const float v = __shfl(val_l, i);
            const float4 f = ((const float4*)(token_ft + (size_t)c * DDIM))[lane];
            acc0.x += f.x * v; acc0.y += f.y * v; acc0.z += f.z * v; acc0.w += f.w * v;
        }
    }

    acc0.x += acc1.x; acc0.y += acc1.y; acc0.z += acc1.z; acc0.w += acc1.w;
    // Always store (zeros for empty segments — d_out is poisoned by harness).
    ((float4*)(out + (size_t)row * DDIM))[lane] = acc0;
}

// ---------------------------------------------------------------------------
// Fallback (ws too small): original binary-search kernel. Kept for safety.
// ---------------------------------------------------------------------------
__global__ __launch_bounds__(256) void mention_segsum_kernel(
    const float* __restrict__ token_ft,
    const int*   __restrict__ token_code,
    const int*   __restrict__ spm_rows,
    const float* __restrict__ spm_vals,
    float*       __restrict__ out)
{
    const int wave = threadIdx.x >> 6;
    const int lane = threadIdx.x & 63;
    const int row  = (blockIdx.x << 2) + wave;

    int lo = 0, hi = NNZ;
    while (lo < hi) {
        int mid = (lo + hi) >> 1;
        if (spm_rows[mid] < row) lo = mid + 1; else hi = mid;
    }
    const int start = lo;
    hi = NNZ;
    while (lo < hi) {
        int mid = (lo + hi) >> 1;
        if (spm_rows[mid] < row + 1) lo = mid + 1; else hi = mid;
    }
    const int end = lo;

    float4 acc = make_float4(0.f, 0.f, 0.f, 0.f);
    for (int k = start; k < end; ++k) {
        const int   code = token_code[k];
        const float v    = spm_vals[k];
        const float4 ft = ((const float4*)(token_ft + (size_t)code * DDIM))[lane];
        acc.x += ft.x * v; acc.y += ft.y * v; acc.z += ft.z * v; acc.w += ft.w * v;
    }
    ((float4*)(out + (size_t)row * DDIM))[lane] = acc;
}

extern "C" void kernel_launch(void* const* d_in, const int* in_sizes, int n_in,
                              void* d_out, int out_size, void* d_ws, size_t ws_size,
                              hipStream_t stream) {
    const float* token_ft   = (const float*)d_in[0];
    const int*   token_code = (const int*)d_in[1];
    const int*   spm_rows   = (const int*)d_in[2];
    const float* spm_vals   = (const float*)d_in[3];
    float*       out        = (float*)d_out;

    const size_t need = (size_t)(N_MENTIONS + 1) * sizeof(int);
    if (ws_size >= need) {
        int* row_start = (int*)d_ws;
        // Kernel 1: NNZ+1 threads
        build_row_start_kernel<<<(NNZ + 1 + 255) / 256, 256, 0, stream>>>(
            spm_rows, row_start);
        // Kernel 2: 4 rows (waves) per 256-thread block
        mention_csr_kernel<<<N_MENTIONS / 4, 256, 0, stream>>>(
            token_ft, token_code, spm_vals, row_start, out);
    } else {
        mention_segsum_kernel<<<N_MENTIONS / 4, 256, 0, stream>>>(
            token_ft, token_code, spm_rows, spm_vals, out);
    }
}